// Round 3
// baseline (220.184 us; speedup 1.0000x reference)
//
#include <hip/hip_runtime.h>

#define N_BATCH 4096
#define K_ACT   32
#define D_FEAT  49152
#define BASE    512
#define F0_DIM  768
#define F1_DIM  64

// Kernel 1: R[d, r] = W_aff[r, d] + w_block0[f0[d], r] + w_block1[f1[d], r]
// 32x32 LDS-tiled transpose; coalesced on both sides; w-block gathers are
// L2-resident (1.5MB / 128KB tables).
__global__ __launch_bounds__(256) void build_R_kernel(
    const float* __restrict__ W_aff,
    const float* __restrict__ w0,
    const float* __restrict__ w1,
    const int* __restrict__ f0,
    const int* __restrict__ f1,
    float* __restrict__ R)
{
    __shared__ float tile[32][33];   // +1 pad: conflict-free transpose
    const int d0 = blockIdx.x * 32;  // feature dim
    const int r0 = blockIdx.y * 32;  // BASE dim
    const int tx = threadIdx.x;      // 0..31
    const int ty = threadIdx.y;      // 0..7

#pragma unroll
    for (int i = 0; i < 32; i += 8) {
        tile[ty + i][tx] = W_aff[(size_t)(r0 + ty + i) * D_FEAT + (d0 + tx)];
    }
    __syncthreads();
#pragma unroll
    for (int i = 0; i < 32; i += 8) {
        const int d  = d0 + ty + i;
        const int rr = r0 + tx;
        float v = tile[tx][ty + i];                 // W_aff[rr, d]
        v += w0[(size_t)f0[d] * BASE + rr];
        v += w1[(size_t)f1[d] * BASE + rr];
        R[(size_t)d * BASE + rr] = v;
    }
}

// Kernel 2: out[n, :] = b_aff + sum_k v[n,k] * R[idx[n,k], :]
// One n per 128-thread group (float4 x 128 = 512 outputs). Wave-uniform n so
// idx/val loads become scalar loads. 32 independent float4 gathers per thread.
__global__ __launch_bounds__(256) void gather_out_kernel(
    const float* __restrict__ R,
    const float* __restrict__ x_val,
    const int*   __restrict__ x_idx,
    const float* __restrict__ b_aff,
    float* __restrict__ out)
{
    const int lane = threadIdx.x & 127;   // float4 slot within row
    const int sub  = threadIdx.x >> 7;    // 0..1
    const int n    = blockIdx.x * 2 + sub;

    const float4* Rv = (const float4*)R;
    float4 acc = ((const float4*)b_aff)[lane];

    const int*   idxp = x_idx + (size_t)n * K_ACT;
    const float* valp = x_val + (size_t)n * K_ACT;

#pragma unroll
    for (int k = 0; k < K_ACT; ++k) {
        const int   idx = idxp[k];
        const float v   = valp[k];
        const float4 w = Rv[(size_t)idx * (BASE / 4) + lane];
        acc.x += v * w.x;
        acc.y += v * w.y;
        acc.z += v * w.z;
        acc.w += v * w.w;
    }
    ((float4*)out)[(size_t)n * (BASE / 4) + lane] = acc;
}

// Fallback (only if d_ws can't hold the 96MB R table): direct strided gather.
__global__ __launch_bounds__(512) void direct_kernel(
    const float* __restrict__ x_val,
    const float* __restrict__ W_aff,
    const float* __restrict__ b_aff,
    const float* __restrict__ w0,
    const float* __restrict__ w1,
    const int*   __restrict__ x_idx,
    const int*   __restrict__ f0,
    const int*   __restrict__ f1,
    float* __restrict__ out)
{
    const int n = blockIdx.x;
    const int r = threadIdx.x;  // 0..511
    float acc = b_aff[r];
    for (int k = 0; k < K_ACT; ++k) {
        const int   idx = x_idx[(size_t)n * K_ACT + k];
        const float v   = x_val[(size_t)n * K_ACT + k];
        float w = W_aff[(size_t)r * D_FEAT + idx];
        w += w0[(size_t)f0[idx] * BASE + r];
        w += w1[(size_t)f1[idx] * BASE + r];
        acc += v * w;
    }
    out[(size_t)n * BASE + r] = acc;
}

extern "C" void kernel_launch(void* const* d_in, const int* in_sizes, int n_in,
                              void* d_out, int out_size, void* d_ws, size_t ws_size,
                              hipStream_t stream) {
    const float* x_val = (const float*)d_in[0];
    const float* W_aff = (const float*)d_in[1];
    const float* b_aff = (const float*)d_in[2];
    const float* w0    = (const float*)d_in[3];
    const float* w1    = (const float*)d_in[4];
    const int*   x_idx = (const int*)d_in[5];
    const int*   f0    = (const int*)d_in[6];
    const int*   f1    = (const int*)d_in[7];
    float* out = (float*)d_out;

    const size_t needR = (size_t)D_FEAT * BASE * sizeof(float);  // ~96 MB
    if (ws_size >= needR) {
        float* R = (float*)d_ws;
        dim3 grid(D_FEAT / 32, BASE / 32);
        dim3 block(32, 8);
        build_R_kernel<<<grid, block, 0, stream>>>(W_aff, w0, w1, f0, f1, R);
        gather_out_kernel<<<N_BATCH / 2, 256, 0, stream>>>(R, x_val, x_idx, b_aff, out);
    } else {
        direct_kernel<<<N_BATCH, BASE, 0, stream>>>(x_val, W_aff, b_aff, w0, w1,
                                                    x_idx, f0, f1, out);
    }
}

// Round 5
// 218.011 us; speedup vs baseline: 1.0100x; 1.0100x over previous
//
#include <hip/hip_runtime.h>

#define N_BATCH 4096
#define K_ACT   32
#define D_FEAT  49152
#define BASE    512
#define F0_DIM  768
#define F1_DIM  64

// Kernel 1: R[d, r] = W_aff[r, d] + w_block0[f0[d], r] + w_block1[f1[d], r]
// 64x64 tile, float4 on both global sides. LDS layout: tile[r][d] with the
// d-float4-group XOR-swizzled by (r>>2) so that the phase-2 column gather is
// 2-way bank aliasing (free on CDNA4) and phase-1 writes are conflict-free.
__global__ __launch_bounds__(256) void build_R_kernel(
    const float* __restrict__ W_aff,
    const float* __restrict__ w0,
    const float* __restrict__ w1,
    const int* __restrict__ f0,
    const int* __restrict__ f1,
    float* __restrict__ R)
{
    __shared__ float tile[64 * 64];       // 16 KB
    const int d0 = blockIdx.x * 64;       // feature-dim tile base
    const int r0 = blockIdx.y * 64;       // BASE-dim tile base
    const int t  = threadIdx.x;
    const int q  = t >> 4;                // 0..15
    const int x  = t & 15;                // 0..15

    // Phase 1: read W_aff rows (contiguous in d) as float4, store swizzled.
    const float4* W4 = (const float4*)W_aff;
#pragma unroll
    for (int i = 0; i < 4; ++i) {
        const int rl = q + i * 16;                        // 0..63 (tile r)
        float4 w = W4[(size_t)(r0 + rl) * (D_FEAT / 4) + (d0 >> 2) + x];
        const int sg = x ^ (rl >> 2);                     // swizzled d-group
        ((float4*)tile)[rl * 16 + sg] = w;
    }
    __syncthreads();

    // Phase 2: per d row, gather 4 consecutive r from LDS, add block tables,
    // write R[d, r0+4x .. +3] as float4 (contiguous in r).
    const float4* w0v = (const float4*)w0;
    const float4* w1v = (const float4*)w1;
    float4*       R4  = (float4*)R;
#pragma unroll
    for (int i = 0; i < 4; ++i) {
        const int dl = q + i * 16;                        // 0..63 (tile d)
        const int d  = d0 + dl;
        const int g  = dl >> 2;                           // d float4-group
        const int e  = dl & 3;                            // elem within group
        float4 acc;
        float* accp = (float*)&acc;
#pragma unroll
        for (int j = 0; j < 4; ++j) {
            const int rl = 4 * x + j;                     // (rl>>2) == x
            accp[j] = tile[rl * 64 + ((g ^ x) << 2) + e];
        }
        const int i0 = f0[d];
        const int i1 = f1[d];
        const float4 a0 = w0v[(size_t)i0 * (BASE / 4) + (r0 >> 2) + x];
        const float4 a1 = w1v[(size_t)i1 * (BASE / 4) + (r0 >> 2) + x];
        acc.x += a0.x + a1.x;
        acc.y += a0.y + a1.y;
        acc.z += a0.z + a1.z;
        acc.w += a0.w + a1.w;
        R4[(size_t)d * (BASE / 4) + (r0 >> 2) + x] = acc;
    }
}

// Kernel 2: out[n, :] = b_aff + sum_k v[n,k] * R[idx[n,k], :]
// One n per 128-thread group (float4 x 128 = 512 outputs). 32 independent
// float4 gathers per thread; R rows are 2KB contiguous (coalesced).
__global__ __launch_bounds__(256) void gather_out_kernel(
    const float* __restrict__ R,
    const float* __restrict__ x_val,
    const int*   __restrict__ x_idx,
    const float* __restrict__ b_aff,
    float* __restrict__ out)
{
    const int lane = threadIdx.x & 127;   // float4 slot within row
    const int sub  = threadIdx.x >> 7;    // 0..1
    const int n    = blockIdx.x * 2 + sub;

    const float4* Rv = (const float4*)R;
    float4 acc = ((const float4*)b_aff)[lane];

    const int*   idxp = x_idx + (size_t)n * K_ACT;
    const float* valp = x_val + (size_t)n * K_ACT;

#pragma unroll
    for (int k = 0; k < K_ACT; ++k) {
        const int   idx = idxp[k];
        const float v   = valp[k];
        const float4 w = Rv[(size_t)idx * (BASE / 4) + lane];
        acc.x += v * w.x;
        acc.y += v * w.y;
        acc.z += v * w.z;
        acc.w += v * w.w;
    }
    ((float4*)out)[(size_t)n * (BASE / 4) + lane] = acc;
}

// Fallback (only if d_ws can't hold the 96MB R table): direct strided gather.
__global__ __launch_bounds__(512) void direct_kernel(
    const float* __restrict__ x_val,
    const float* __restrict__ W_aff,
    const float* __restrict__ b_aff,
    const float* __restrict__ w0,
    const float* __restrict__ w1,
    const int*   __restrict__ x_idx,
    const int*   __restrict__ f0,
    const int*   __restrict__ f1,
    float* __restrict__ out)
{
    const int n = blockIdx.x;
    const int r = threadIdx.x;  // 0..511
    float acc = b_aff[r];
    for (int k = 0; k < K_ACT; ++k) {
        const int   idx = x_idx[(size_t)n * K_ACT + k];
        const float v   = x_val[(size_t)n * K_ACT + k];
        float w = W_aff[(size_t)r * D_FEAT + idx];
        w += w0[(size_t)f0[idx] * BASE + r];
        w += w1[(size_t)f1[idx] * BASE + r];
        acc += v * w;
    }
    out[(size_t)n * BASE + r] = acc;
}

extern "C" void kernel_launch(void* const* d_in, const int* in_sizes, int n_in,
                              void* d_out, int out_size, void* d_ws, size_t ws_size,
                              hipStream_t stream) {
    const float* x_val = (const float*)d_in[0];
    const float* W_aff = (const float*)d_in[1];
    const float* b_aff = (const float*)d_in[2];
    const float* w0    = (const float*)d_in[3];
    const float* w1    = (const float*)d_in[4];
    const int*   x_idx = (const int*)d_in[5];
    const int*   f0    = (const int*)d_in[6];
    const int*   f1    = (const int*)d_in[7];
    float* out = (float*)d_out;

    const size_t needR = (size_t)D_FEAT * BASE * sizeof(float);  // ~96 MB
    if (ws_size >= needR) {
        float* R = (float*)d_ws;
        dim3 grid(D_FEAT / 64, BASE / 64);   // 768 x 8
        build_R_kernel<<<grid, 256, 0, stream>>>(W_aff, w0, w1, f0, f1, R);
        gather_out_kernel<<<N_BATCH / 2, 256, 0, stream>>>(R, x_val, x_idx, b_aff, out);
    } else {
        direct_kernel<<<N_BATCH, BASE, 0, stream>>>(x_val, W_aff, b_aff, w0, w1,
                                                    x_idx, f0, f1, out);
    }
}

// Round 6
// 195.114 us; speedup vs baseline: 1.1285x; 1.1174x over previous
//
#include <hip/hip_runtime.h>

#define N_BATCH 4096
#define K_ACT   32
#define D_FEAT  49152
#define BASE    512

typedef unsigned short ushort_t;
typedef __attribute__((ext_vector_type(8))) unsigned short ushort8;

__device__ __forceinline__ ushort_t f2bf(float f) {
    unsigned u = __builtin_bit_cast(unsigned, f);
    u += 0x7FFFu + ((u >> 16) & 1u);          // round-to-nearest-even
    return (ushort_t)(u >> 16);
}

// Kernel 1: Rb[d, r] = bf16( W_aff[r, d] + w0[f0[d], r] + w1[f1[d], r] )
// 64x64 tile. blockIdx.x = r-tile (FAST, only 8) so concurrently-running
// blocks complete full contiguous R rows -> write locality.
// LDS: tile[r][d] with d-float4-group XOR-swizzled by (r>>2).
__global__ __launch_bounds__(256) void build_R_kernel(
    const float* __restrict__ W_aff,
    const float* __restrict__ w0,
    const float* __restrict__ w1,
    const int* __restrict__ f0,
    const int* __restrict__ f1,
    ushort_t* __restrict__ Rb)
{
    __shared__ float tile[64 * 64];       // 16 KB
    const int r0 = blockIdx.x * 64;       // fast dim: 8 r-tiles
    const int d0 = blockIdx.y * 64;       // slow dim: 768 d-tiles
    const int t  = threadIdx.x;

    // Phase 1: read W_aff rows (contiguous in d) as float4, store swizzled.
    {
        const int q = t >> 4;             // 0..15 (tile r stride 16)
        const int x = t & 15;             // 0..15 (d float4-group)
        const float4* W4 = (const float4*)W_aff;
#pragma unroll
        for (int i = 0; i < 4; ++i) {
            const int rl = q + i * 16;
            float4 w = W4[(size_t)(r0 + rl) * (D_FEAT / 4) + (d0 >> 2) + x];
            ((float4*)tile)[rl * 16 + (x ^ (rl >> 2))] = w;
        }
    }
    __syncthreads();

    // Phase 2: thread covers 8 consecutive r (16B bf16 store) for 2 d values.
    const int rg = t & 7;                 // 8 groups x 8 r = 64 r
    const int dq = t >> 3;                // 0..31
    const float4* w0v = (const float4*)w0;
    const float4* w1v = (const float4*)w1;
#pragma unroll
    for (int i = 0; i < 2; ++i) {
        const int dl = dq + 32 * i;       // 0..63 (tile d)
        const int d  = d0 + dl;
        const int i0 = f0[d];
        const int i1 = f1[d];
        float a[8];
#pragma unroll
        for (int j = 0; j < 8; ++j) {
            const int rl = 8 * rg + j;
            a[j] = tile[rl * 64 + (((dl >> 2) ^ (rl >> 2)) << 2) + (dl & 3)];
        }
        const float4 b0 = w0v[(size_t)i0 * (BASE / 4) + (r0 >> 2) + 2 * rg];
        const float4 b1 = w0v[(size_t)i0 * (BASE / 4) + (r0 >> 2) + 2 * rg + 1];
        const float4 c0 = w1v[(size_t)i1 * (BASE / 4) + (r0 >> 2) + 2 * rg];
        const float4 c1 = w1v[(size_t)i1 * (BASE / 4) + (r0 >> 2) + 2 * rg + 1];
        a[0] += b0.x + c0.x;  a[1] += b0.y + c0.y;
        a[2] += b0.z + c0.z;  a[3] += b0.w + c0.w;
        a[4] += b1.x + c1.x;  a[5] += b1.y + c1.y;
        a[6] += b1.z + c1.z;  a[7] += b1.w + c1.w;
        ushort8 o;
#pragma unroll
        for (int j = 0; j < 8; ++j) o[j] = f2bf(a[j]);
        *(ushort8*)&Rb[(size_t)d * BASE + r0 + 8 * rg] = o;
    }
}

// Kernel 2: out[n, :] = b_aff + sum_k v[n,k] * Rb[idx[n,k], :]
// One n per 64-lane wave; lane covers 8 outputs (ushort8 = 16B load, so each
// k-iteration reads the 1KB bf16 R row fully coalesced).
__global__ __launch_bounds__(256) void gather_out_kernel(
    const ushort_t* __restrict__ Rb,
    const float* __restrict__ x_val,
    const int*   __restrict__ x_idx,
    const float* __restrict__ b_aff,
    float* __restrict__ out)
{
    const int lane = threadIdx.x & 63;
    const int wv   = threadIdx.x >> 6;     // 0..3
    const int n    = blockIdx.x * 4 + wv;

    float acc[8];
    {
        const float4 bb0 = ((const float4*)b_aff)[2 * lane];
        const float4 bb1 = ((const float4*)b_aff)[2 * lane + 1];
        acc[0] = bb0.x; acc[1] = bb0.y; acc[2] = bb0.z; acc[3] = bb0.w;
        acc[4] = bb1.x; acc[5] = bb1.y; acc[6] = bb1.z; acc[7] = bb1.w;
    }

    const int*   idxp = x_idx + (size_t)n * K_ACT;
    const float* valp = x_val + (size_t)n * K_ACT;

#pragma unroll
    for (int k = 0; k < K_ACT; ++k) {
        const int   idx = idxp[k];
        const float v   = valp[k];
        const ushort8 w = *(const ushort8*)&Rb[(size_t)idx * BASE + 8 * lane];
#pragma unroll
        for (int j = 0; j < 8; ++j) {
            const float wf = __builtin_bit_cast(float, (unsigned)w[j] << 16);
            acc[j] = fmaf(v, wf, acc[j]);
        }
    }

    float4 o0, o1;
    o0.x = acc[0]; o0.y = acc[1]; o0.z = acc[2]; o0.w = acc[3];
    o1.x = acc[4]; o1.y = acc[5]; o1.z = acc[6]; o1.w = acc[7];
    ((float4*)out)[(size_t)n * (BASE / 4) + 2 * lane]     = o0;
    ((float4*)out)[(size_t)n * (BASE / 4) + 2 * lane + 1] = o1;
}

// Fallback (only if d_ws can't hold the 48MB bf16 R table): direct gather.
__global__ __launch_bounds__(512) void direct_kernel(
    const float* __restrict__ x_val,
    const float* __restrict__ W_aff,
    const float* __restrict__ b_aff,
    const float* __restrict__ w0,
    const float* __restrict__ w1,
    const int*   __restrict__ x_idx,
    const int*   __restrict__ f0,
    const int*   __restrict__ f1,
    float* __restrict__ out)
{
    const int n = blockIdx.x;
    const int r = threadIdx.x;  // 0..511
    float acc = b_aff[r];
    for (int k = 0; k < K_ACT; ++k) {
        const int   idx = x_idx[(size_t)n * K_ACT + k];
        const float v   = x_val[(size_t)n * K_ACT + k];
        float w = W_aff[(size_t)r * D_FEAT + idx];
        w += w0[(size_t)f0[idx] * BASE + r];
        w += w1[(size_t)f1[idx] * BASE + r];
        acc += v * w;
    }
    out[(size_t)n * BASE + r] = acc;
}

extern "C" void kernel_launch(void* const* d_in, const int* in_sizes, int n_in,
                              void* d_out, int out_size, void* d_ws, size_t ws_size,
                              hipStream_t stream) {
    const float* x_val = (const float*)d_in[0];
    const float* W_aff = (const float*)d_in[1];
    const float* b_aff = (const float*)d_in[2];
    const float* w0    = (const float*)d_in[3];
    const float* w1    = (const float*)d_in[4];
    const int*   x_idx = (const int*)d_in[5];
    const int*   f0    = (const int*)d_in[6];
    const int*   f1    = (const int*)d_in[7];
    float* out = (float*)d_out;

    const size_t needR = (size_t)D_FEAT * BASE * sizeof(ushort_t);  // ~48 MB
    if (ws_size >= needR) {
        ushort_t* Rb = (ushort_t*)d_ws;
        dim3 grid(BASE / 64, D_FEAT / 64);   // 8 (fast, r) x 768 (slow, d)
        build_R_kernel<<<grid, 256, 0, stream>>>(W_aff, w0, w1, f0, f1, Rb);
        gather_out_kernel<<<N_BATCH / 4, 256, 0, stream>>>(Rb, x_val, x_idx, b_aff, out);
    } else {
        direct_kernel<<<N_BATCH, BASE, 0, stream>>>(x_val, W_aff, b_aff, w0, w1,
                                                    x_idx, f0, f1, out);
    }
}